// Round 1
// baseline (453.362 us; speedup 1.0000x reference)
//
#include <hip/hip_runtime.h>

// Window attention: B=4096, L=49, C=256, H=8, D=32
// k1: fused qkv + attention per window -> writes O (fp32) to d_out
// k2: proj GEMM in-place on d_out
// prep: pre-swizzle weights to bf16 MFMA B-fragment order in d_ws + bias table

typedef short s8v __attribute__((ext_vector_type(8)));   // 8 bf16 (4 VGPRs) MFMA A/B frag
typedef float f4  __attribute__((ext_vector_type(4)));   // MFMA C/D frag

#define MFMA(a,b,c) __builtin_amdgcn_mfma_f32_16x16x32_bf16((a),(b),(c),0,0,0)

__device__ __forceinline__ unsigned short f2bf(float f) {
    unsigned u = __float_as_uint(f);
    u = u + 0x7fffu + ((u >> 16) & 1u);   // round-to-nearest-even
    return (unsigned short)(u >> 16);
}

// ---------------- prep: weight swizzle + bias table ----------------
// wq layout: [nt=48][ks=8][lane=64][j=8] ; element = qkv_w[ks*32+(lane>>4)*8+j][nt*16+(lane&15)]
// wp layout: same with nt=16 over proj_w
// biasT: [h=8][key=64][query=64] fp32, -1e30 for key>=49 or query>=49
__global__ void prep(const float* __restrict__ qkv_w, const float* __restrict__ proj_w,
                     const float* __restrict__ rel_bias, const int* __restrict__ rel_idx,
                     unsigned short* __restrict__ wq, unsigned short* __restrict__ wp,
                     float* __restrict__ biasT)
{
    int idx = blockIdx.x * blockDim.x + threadIdx.x;
    int stride = gridDim.x * blockDim.x;
    for (int i = idx; i < 48*8*64*8; i += stride) {
        int j = i & 7, l = (i >> 3) & 63, ks = (i >> 9) & 7, nt = i >> 12;
        int k = ks*32 + (l >> 4)*8 + j;
        int n = nt*16 + (l & 15);
        wq[i] = f2bf(qkv_w[k*768 + n]);
    }
    for (int i = idx; i < 16*8*64*8; i += stride) {
        int j = i & 7, l = (i >> 3) & 63, ks = (i >> 9) & 7, nt = i >> 12;
        int k = ks*32 + (l >> 4)*8 + j;
        int n = nt*16 + (l & 15);
        wp[i] = f2bf(proj_w[k*256 + n]);
    }
    for (int i = idx; i < 8*64*64; i += stride) {
        int q = i & 63, m = (i >> 6) & 63, h = i >> 12;
        float v = -1e30f;
        if (m < 49 && q < 49) v = rel_bias[rel_idx[q*49 + m]*8 + h];
        biasT[i] = v;
    }
}

// ---------------- k1: qkv + attention ----------------
__global__ __launch_bounds__(256, 2) void k1(
    const float* __restrict__ x, const float* __restrict__ qkv_b,
    const unsigned short* __restrict__ wq, const float* __restrict__ biasT,
    float* __restrict__ out)
{
    __shared__ __align__(16) unsigned short xs[64][264];      // x tile, bf16, rows 49..63 zero
    __shared__ __align__(16) unsigned short qsh[2][64][40];   // q*scale, row-major [m][d]
    __shared__ __align__(16) unsigned short ksh[2][64][40];   // k, row-major [m][d]
    __shared__ __align__(16) unsigned short vsh[2][32][72];   // v transposed [d][perm(m)]
    // total 63488 B

    const int b    = blockIdx.x;
    const int tid  = threadIdx.x;
    const int w    = tid >> 6;
    const int lane = tid & 63;
    const int ln   = lane & 15;
    const int g    = lane >> 4;

    const float* xb = x + (size_t)b * (49*256);

    // stage x -> bf16 LDS (zero-pad rows 49..63)
    for (int i = tid; i < 64*64; i += 256) {
        int r = i >> 6, c4 = i & 63;
        float4 v = make_float4(0.f, 0.f, 0.f, 0.f);
        if (r < 49) v = ((const float4*)xb)[r*64 + c4];
        unsigned short* p = &xs[r][c4*4];
        p[0] = f2bf(v.x); p[1] = f2bf(v.y); p[2] = f2bf(v.z); p[3] = f2bf(v.w);
    }
    __syncthreads();

    const float scale = 0.17677669529663687f;  // 1/sqrt(32)

    for (int ph = 0; ph < 4; ++ph) {           // head pair: heads 2ph, 2ph+1
        // ---- QKV GEMM: 12 n-tiles for this pair; wave does 3 ----
        int nts[3];
        #pragma unroll
        for (int t = 0; t < 3; ++t) {
            int qi = 3*w + t;
            nts[t] = (qi >> 2)*16 + 4*ph + (qi & 3);   // which*16 + 4*ph + sub
        }
        f4 acc[4][3];
        #pragma unroll
        for (int mt = 0; mt < 4; ++mt)
            #pragma unroll
            for (int t = 0; t < 3; ++t)
                acc[mt][t] = (f4){0.f, 0.f, 0.f, 0.f};

        #pragma unroll 2
        for (int ks = 0; ks < 8; ++ks) {
            s8v av[4], bv[3];
            #pragma unroll
            for (int mt = 0; mt < 4; ++mt)
                av[mt] = *(const s8v*)&xs[mt*16 + ln][ks*32 + g*8];
            #pragma unroll
            for (int t = 0; t < 3; ++t)
                bv[t] = *(const s8v*)&wq[(size_t)((nts[t]*8 + ks)*64 + lane) * 8];
            #pragma unroll
            for (int mt = 0; mt < 4; ++mt)
                #pragma unroll
                for (int t = 0; t < 3; ++t)
                    acc[mt][t] = MFMA(av[mt], bv[t], acc[mt][t]);
        }
        // epilogue: +qkv_b, store q/k/v into LDS
        #pragma unroll
        for (int t = 0; t < 3; ++t) {
            int nt = nts[t];
            int which = nt >> 4;                 // 0=q 1=k 2=v
            int hl = ((nt & 15) >> 1) & 1;       // head within pair
            int dh = nt & 1;                     // d half
            float bias = qkv_b[nt*16 + ln];
            int d = dh*16 + ln;
            #pragma unroll
            for (int mt = 0; mt < 4; ++mt) {
                #pragma unroll
                for (int r = 0; r < 4; ++r) {
                    float v = acc[mt][t][r] + bias;
                    int m = mt*16 + g*4 + r;
                    if (which == 0)      qsh[hl][m][d] = f2bf(v * scale);
                    else if (which == 1) ksh[hl][m][d] = f2bf(v);
                    else {
                        // permuted column so PV B-frag (kappa2) is one contiguous b128
                        int ca = (mt >> 1)*32 + g*8 + (mt & 1)*4 + r;
                        vsh[hl][d][ca] = f2bf(v);
                    }
                }
            }
        }
        __syncthreads();

        // ---- attention: wave -> head hl=w>>1, query tiles {2*(w&1), 2*(w&1)+1} ----
        {
            const int hl  = w >> 1;
            const int hg  = 2*ph + hl;
            const int qt0 = 2*(w & 1);

            // swapped QK^T: S^T[key][query] = mfma(K, Qscaled)
            f4 st[4][2];
            #pragma unroll
            for (int kt = 0; kt < 4; ++kt) {
                s8v ak = *(const s8v*)&ksh[hl][kt*16 + ln][g*8];
                #pragma unroll
                for (int qq = 0; qq < 2; ++qq) {
                    s8v bq = *(const s8v*)&qsh[hl][(qt0+qq)*16 + ln][g*8];
                    f4 z = (f4){0.f, 0.f, 0.f, 0.f};
                    st[kt][qq] = MFMA(ak, bq, z);
                }
            }

            // softmax over keys (rows of S^T); lane's column = query qt*16+ln
            float pr[2][16];
            #pragma unroll
            for (int qq = 0; qq < 2; ++qq) {
                int q = (qt0+qq)*16 + ln;
                float mx = -3.0e38f;
                #pragma unroll
                for (int kt = 0; kt < 4; ++kt)
                    #pragma unroll
                    for (int r = 0; r < 4; ++r) {
                        int key = kt*16 + g*4 + r;
                        float s = st[kt][qq][r] + biasT[(hg*64 + key)*64 + q];
                        pr[qq][kt*4 + r] = s;
                        mx = fmaxf(mx, s);
                    }
                mx = fmaxf(mx, __shfl_xor(mx, 16));
                mx = fmaxf(mx, __shfl_xor(mx, 32));
                float sum = 0.f;
                #pragma unroll
                for (int i = 0; i < 16; ++i) {
                    float e = __expf(pr[qq][i] - mx);
                    pr[qq][i] = e;
                    sum += e;
                }
                sum += __shfl_xor(sum, 16);
                sum += __shfl_xor(sum, 32);
                float rinv = 1.f / sum;
                #pragma unroll
                for (int i = 0; i < 16; ++i) pr[qq][i] *= rinv;
            }

            // PV with kappa2(g,j)=16*(j>>2)+4g+(j&3): A-frag is in-lane repack of pr
            #pragma unroll
            for (int qq = 0; qq < 2; ++qq) {
                f4 oacc[2];
                oacc[0] = (f4){0.f, 0.f, 0.f, 0.f};
                oacc[1] = (f4){0.f, 0.f, 0.f, 0.f};
                #pragma unroll
                for (int ksp = 0; ksp < 2; ++ksp) {
                    s8v pa;
                    #pragma unroll
                    for (int j = 0; j < 8; ++j) {
                        int kt = 2*ksp + (j >> 2);
                        int r  = j & 3;
                        pa[j] = (short)f2bf(pr[qq][kt*4 + r]);
                    }
                    #pragma unroll
                    for (int dt = 0; dt < 2; ++dt) {
                        s8v bv2 = *(const s8v*)&vsh[hl][dt*16 + ln][ksp*32 + g*8];
                        oacc[dt] = MFMA(pa, bv2, oacc[dt]);
                    }
                }
                #pragma unroll
                for (int dt = 0; dt < 2; ++dt) {
                    int c = hg*32 + dt*16 + ln;
                    #pragma unroll
                    for (int r = 0; r < 4; ++r) {
                        int q = (qt0+qq)*16 + g*4 + r;
                        if (q < 49)
                            out[((size_t)b*49 + q)*256 + c] = oacc[dt][r];
                    }
                }
            }
        }
        __syncthreads();
    }
}

// ---------------- k2: proj GEMM, in-place on d_out ----------------
__global__ __launch_bounds__(256, 2) void k2(
    const unsigned short* __restrict__ wp, const float* __restrict__ proj_b,
    float* __restrict__ out)
{
    __shared__ __align__(16) unsigned short os[64][264];
    const int b    = blockIdx.x;
    const int tid  = threadIdx.x;
    const int w    = tid >> 6;
    const int lane = tid & 63;
    const int ln   = lane & 15;
    const int g    = lane >> 4;

    float* ob = out + (size_t)b * (49*256);

    for (int i = tid; i < 64*64; i += 256) {
        int r = i >> 6, c4 = i & 63;
        float4 v = make_float4(0.f, 0.f, 0.f, 0.f);
        if (r < 49) v = ((const float4*)ob)[r*64 + c4];
        unsigned short* p = &os[r][c4*4];
        p[0] = f2bf(v.x); p[1] = f2bf(v.y); p[2] = f2bf(v.z); p[3] = f2bf(v.w);
    }
    __syncthreads();

    f4 acc[4][4];
    #pragma unroll
    for (int mt = 0; mt < 4; ++mt)
        #pragma unroll
        for (int t = 0; t < 4; ++t)
            acc[mt][t] = (f4){0.f, 0.f, 0.f, 0.f};

    #pragma unroll 2
    for (int ks = 0; ks < 8; ++ks) {
        s8v av[4], bv[4];
        #pragma unroll
        for (int mt = 0; mt < 4; ++mt)
            av[mt] = *(const s8v*)&os[mt*16 + ln][ks*32 + g*8];
        #pragma unroll
        for (int t = 0; t < 4; ++t) {
            int nt = w*4 + t;
            bv[t] = *(const s8v*)&wp[(size_t)((nt*8 + ks)*64 + lane) * 8];
        }
        #pragma unroll
        for (int mt = 0; mt < 4; ++mt)
            #pragma unroll
            for (int t = 0; t < 4; ++t)
                acc[mt][t] = MFMA(av[mt], bv[t], acc[mt][t]);
    }

    #pragma unroll
    for (int t = 0; t < 4; ++t) {
        int n = (w*4 + t)*16 + ln;
        float pb = proj_b[n];
        #pragma unroll
        for (int mt = 0; mt < 4; ++mt) {
            #pragma unroll
            for (int r = 0; r < 4; ++r) {
                int q = mt*16 + g*4 + r;
                if (q < 49)
                    ob[q*256 + n] = acc[mt][t][r] + pb;
            }
        }
    }
}

extern "C" void kernel_launch(void* const* d_in, const int* in_sizes, int n_in,
                              void* d_out, int out_size, void* d_ws, size_t ws_size,
                              hipStream_t stream)
{
    (void)n_in; (void)out_size; (void)ws_size;
    const float* x        = (const float*)d_in[0];
    const int*   rel_idx  = (const int*)  d_in[1];
    const float* qkv_w    = (const float*)d_in[2];
    const float* qkv_b    = (const float*)d_in[3];
    const float* rel_bias = (const float*)d_in[4];
    const float* proj_w   = (const float*)d_in[5];
    const float* proj_b   = (const float*)d_in[6];
    float* out = (float*)d_out;

    const int B = in_sizes[0] / (49*256);

    unsigned short* wq = (unsigned short*)d_ws;                     // 393216 B
    unsigned short* wp = wq + 48*8*64*8;                            // 131072 B
    float* biasT = (float*)((char*)d_ws + 524288);                  // 131072 B

    prep<<<256, 256, 0, stream>>>(qkv_w, proj_w, rel_bias, rel_idx, wq, wp, biasT);
    k1<<<B, 256, 0, stream>>>(x, qkv_b, wq, biasT, out);
    k2<<<B, 256, 0, stream>>>(wp, proj_b, out);
}